// Round 3
// baseline (273.575 us; speedup 1.0000x reference)
//
#include <hip/hip_runtime.h>
#include <math.h>

#define NTOK 2048
#define DMODEL 1024
#define NHEAD 16
#define DHEAD 64

typedef _Float16 f16x8 __attribute__((ext_vector_type(8)));
typedef _Float16 f16x4 __attribute__((ext_vector_type(4)));
typedef float f32x4 __attribute__((ext_vector_type(4)));

__device__ __forceinline__ void split16(float x, _Float16& hi, _Float16& lo) {
    hi = (_Float16)x;
    lo = (_Float16)(x - (float)hi);
}

// 8B-aligned LDS vector helpers (rows are 136B apart -> only 8B aligned)
__device__ __forceinline__ f16x8 lds_ld8(const _Float16* p) {
    f16x8 r;
    *(f16x4*)&r       = *(const f16x4*)p;
    *((f16x4*)&r + 1) = *(const f16x4*)(p + 4);
    return r;
}
__device__ __forceinline__ void lds_st8(_Float16* p, f16x8 v) {
    *(f16x4*)p       = *(f16x4*)&v;
    *((f16x4*)p + 1) = *((f16x4*)&v + 1);
}

// ---------- prep: W[k][n] f32 -> Wt_hi/Wt_lo [n][k] f16, 4 matrices ----------
__global__ void __launch_bounds__(256) prep_w_kernel(
        const float* __restrict__ Wq, const float* __restrict__ Wk,
        const float* __restrict__ Wv, const float* __restrict__ Wo,
        _Float16* __restrict__ Wt) {
    __shared__ float T[32][33];
    const int z = blockIdx.z;
    const float* W = (z == 0) ? Wq : (z == 1) ? Wk : (z == 2) ? Wv : Wo;
    _Float16* Whi = Wt + (size_t)z * 2 * 1024 * 1024;
    _Float16* Wlo = Whi + (size_t)1024 * 1024;
    const int t = threadIdx.x;
    const int k0 = blockIdx.y * 32, n0 = blockIdx.x * 32;
    const int r = t >> 3, c4 = (t & 7) * 4;
    const float4 v = *(const float4*)(W + (size_t)(k0 + r) * DMODEL + n0 + c4);
    T[r][c4 + 0] = v.x; T[r][c4 + 1] = v.y; T[r][c4 + 2] = v.z; T[r][c4 + 3] = v.w;
    __syncthreads();
    f16x4 hv, lv;
#pragma unroll
    for (int j = 0; j < 4; ++j) {
        _Float16 h, l;
        split16(T[c4 + j][r], h, l);
        hv[j] = h; lv[j] = l;
    }
    *(f16x4*)(Whi + (size_t)(n0 + r) * DMODEL + k0 + c4) = hv;
    *(f16x4*)(Wlo + (size_t)(n0 + r) * DMODEL + k0 + c4) = lv;
}

// ---------- QKV projection: split-f16 MFMA GEMM ----------
__global__ void __launch_bounds__(256) qkv_mfma_kernel(
        const float* __restrict__ Aq, const float* __restrict__ Ak, const float* __restrict__ Av,
        const _Float16* __restrict__ Wt,
        const float* __restrict__ bq, const float* __restrict__ bk, const float* __restrict__ bv,
        _Float16* __restrict__ Qh, _Float16* __restrict__ Ql,
        _Float16* __restrict__ Kh, _Float16* __restrict__ Kl,
        _Float16* __restrict__ Vth, _Float16* __restrict__ Vtl) {
    __shared__ _Float16 Ah[128][40], Al[128][40], Bh[128][40], Bl[128][40];
    const int z = blockIdx.z;
    const float* A = (z == 0) ? Aq : (z == 1) ? Ak : Av;
    const _Float16* WH = Wt + (size_t)z * 2 * 1024 * 1024;
    const _Float16* WL = WH + (size_t)1024 * 1024;
    const float* bias = (z == 0) ? bq : (z == 1) ? bk : bv;

    const int t = threadIdx.x;
    const int l = t & 63, wid = t >> 6;
    const int lr = l & 15, lk = l >> 4;
    const int m0 = blockIdx.y * 128, n0 = blockIdx.x * 128;
    const int wm = (wid >> 1) * 64, wn = (wid & 1) * 64;

    f32x4 acc[4][4];
#pragma unroll
    for (int mi = 0; mi < 4; ++mi)
#pragma unroll
        for (int ni = 0; ni < 4; ++ni)
#pragma unroll
            for (int e = 0; e < 4; ++e) acc[mi][ni][e] = 0.f;

    for (int k0 = 0; k0 < DMODEL; k0 += 32) {
        __syncthreads();
#pragma unroll
        for (int p = 0; p < 4; ++p) {                    // A: f32 -> hi/lo f16
            const int idx = t + p * 256;
            const int r = idx >> 3, c4 = (idx & 7) * 4;
            const float4 v = *(const float4*)(A + (size_t)(m0 + r) * DMODEL + k0 + c4);
            f16x4 hv, lv; _Float16 h, lo;
            split16(v.x, h, lo); hv[0] = h; lv[0] = lo;
            split16(v.y, h, lo); hv[1] = h; lv[1] = lo;
            split16(v.z, h, lo); hv[2] = h; lv[2] = lo;
            split16(v.w, h, lo); hv[3] = h; lv[3] = lo;
            *(f16x4*)&Ah[r][c4] = hv;
            *(f16x4*)&Al[r][c4] = lv;
        }
#pragma unroll
        for (int p = 0; p < 2; ++p) {                    // B: prepped f16 direct
            const int idx = t + p * 256;
            const int r = idx >> 2, c8 = (idx & 3) * 8;
            *(f16x8*)&Bh[r][c8] = *(const f16x8*)(WH + (size_t)(n0 + r) * DMODEL + k0 + c8);
            *(f16x8*)&Bl[r][c8] = *(const f16x8*)(WL + (size_t)(n0 + r) * DMODEL + k0 + c8);
        }
        __syncthreads();

        f16x8 ah[4], al[4], bh[4], bl[4];
#pragma unroll
        for (int i = 0; i < 4; ++i) {
            ah[i] = *(f16x8*)&Ah[wm + i * 16 + lr][lk * 8];
            al[i] = *(f16x8*)&Al[wm + i * 16 + lr][lk * 8];
            bh[i] = *(f16x8*)&Bh[wn + i * 16 + lr][lk * 8];
            bl[i] = *(f16x8*)&Bl[wn + i * 16 + lr][lk * 8];
        }
#pragma unroll
        for (int mi = 0; mi < 4; ++mi)
#pragma unroll
            for (int ni = 0; ni < 4; ++ni) {
                acc[mi][ni] = __builtin_amdgcn_mfma_f32_16x16x32_f16(ah[mi], bh[ni], acc[mi][ni], 0, 0, 0);
                acc[mi][ni] = __builtin_amdgcn_mfma_f32_16x16x32_f16(ah[mi], bl[ni], acc[mi][ni], 0, 0, 0);
                acc[mi][ni] = __builtin_amdgcn_mfma_f32_16x16x32_f16(al[mi], bh[ni], acc[mi][ni], 0, 0, 0);
            }
    }

#pragma unroll
    for (int ni = 0; ni < 4; ++ni) {
        const int col = n0 + wn + ni * 16 + lr;
        const float bv_ = bias[col];
#pragma unroll
        for (int mi = 0; mi < 4; ++mi) {
            if (z == 2) {
                f16x4 hv, lv;
#pragma unroll
                for (int i = 0; i < 4; ++i) {
                    _Float16 h, lo;
                    split16(acc[mi][ni][i] + bv_, h, lo);
                    hv[i] = h; lv[i] = lo;
                }
                const int row = m0 + wm + mi * 16 + lk * 4;
                *(f16x4*)(Vth + (size_t)col * NTOK + row) = hv;
                *(f16x4*)(Vtl + (size_t)col * NTOK + row) = lv;
            } else {
#pragma unroll
                for (int i = 0; i < 4; ++i) {
                    const int row = m0 + wm + mi * 16 + lk * 4 + i;
                    float v = acc[mi][ni][i] + bv_;
                    if (z == 0) v *= 0.125f;
                    _Float16 h, lo;
                    split16(v, h, lo);
                    if (z == 0) { Qh[(size_t)row * DMODEL + col] = h; Ql[(size_t)row * DMODEL + col] = lo; }
                    else        { Kh[(size_t)row * DMODEL + col] = h; Kl[(size_t)row * DMODEL + col] = lo; }
                }
            }
        }
    }
}

// ---------- fused attention: 2-pass, 35KB LDS (4 blocks/CU), ping-pong + P-aliasing ----------
__global__ void __launch_bounds__(256, 4) attn_kernel(
        const _Float16* __restrict__ Qh, const _Float16* __restrict__ Ql,
        const _Float16* __restrict__ Kh, const _Float16* __restrict__ Kl,
        const _Float16* __restrict__ Vth, const _Float16* __restrict__ Vtl,
        float* __restrict__ attn, _Float16* __restrict__ Xh, _Float16* __restrict__ Xl) {
    // KB[buf][hi/lo][row][col]; pass1: K ping-pongs bufs; pass2: K=buf0, V=buf1, P aliases buf0
    __shared__ _Float16 KB[2][2][64][68];
    const int t = threadIdx.x;
    const int l = t & 63, wid = t >> 6;
    const int lr = l & 15, lk = l >> 4;
    const int h = blockIdx.y;
    const int rw = blockIdx.x * 64 + wid * 16;

    const int sjr = t >> 3;          // staging row (p adds 32)
    const int sc8 = (t & 7) * 8;     // staging col

    f16x8 qh[2], qlo[2];
#pragma unroll
    for (int s = 0; s < 2; ++s) {
        qh[s]  = *(const f16x8*)(Qh + (size_t)(rw + lr) * DMODEL + h * DHEAD + s * 32 + lk * 8);
        qlo[s] = *(const f16x8*)(Ql + (size_t)(rw + lr) * DMODEL + h * DHEAD + s * 32 + lk * 8);
    }

    float m[4], lsum[4];
#pragma unroll
    for (int i = 0; i < 4; ++i) { m[i] = -1e30f; lsum[i] = 0.f; }

    // ---- pass 1: stats only, K ping-pong, 1 barrier/tile ----
#pragma unroll
    for (int p = 0; p < 2; ++p) {
        const int jr = sjr + p * 32;
        lds_st8(&KB[0][0][jr][sc8], *(const f16x8*)(Kh + (size_t)jr * DMODEL + h * DHEAD + sc8));
        lds_st8(&KB[0][1][jr][sc8], *(const f16x8*)(Kl + (size_t)jr * DMODEL + h * DHEAD + sc8));
    }
    for (int tt = 0; tt < 32; ++tt) {
        __syncthreads();
        const int cur = tt & 1;
        if (tt + 1 < 32) {
            const int j0n = (tt + 1) * 64;
#pragma unroll
            for (int p = 0; p < 2; ++p) {
                const int jr = sjr + p * 32;
                lds_st8(&KB[cur ^ 1][0][jr][sc8], *(const f16x8*)(Kh + (size_t)(j0n + jr) * DMODEL + h * DHEAD + sc8));
                lds_st8(&KB[cur ^ 1][1][jr][sc8], *(const f16x8*)(Kl + (size_t)(j0n + jr) * DMODEL + h * DHEAD + sc8));
            }
        }
        f32x4 s[4];
#pragma unroll
        for (int jt = 0; jt < 4; ++jt)
#pragma unroll
            for (int e = 0; e < 4; ++e) s[jt][e] = 0.f;
        __builtin_amdgcn_s_setprio(1);
#pragma unroll
        for (int jt = 0; jt < 4; ++jt)
#pragma unroll
            for (int ks = 0; ks < 2; ++ks) {
                const f16x8 kh = lds_ld8(&KB[cur][0][jt * 16 + lr][ks * 32 + lk * 8]);
                const f16x8 kl = lds_ld8(&KB[cur][1][jt * 16 + lr][ks * 32 + lk * 8]);
                s[jt] = __builtin_amdgcn_mfma_f32_16x16x32_f16(qh[ks], kh, s[jt], 0, 0, 0);
                s[jt] = __builtin_amdgcn_mfma_f32_16x16x32_f16(qh[ks], kl, s[jt], 0, 0, 0);
                s[jt] = __builtin_amdgcn_mfma_f32_16x16x32_f16(qlo[ks], kh, s[jt], 0, 0, 0);
            }
        __builtin_amdgcn_s_setprio(0);
#pragma unroll
        for (int i = 0; i < 4; ++i) {
            float v = fmaxf(fmaxf(s[0][i], s[1][i]), fmaxf(s[2][i], s[3][i]));
#pragma unroll
            for (int o = 1; o < 16; o <<= 1) v = fmaxf(v, __shfl_xor(v, o, 16));
            const float mn = fmaxf(m[i], v);
            float e = __expf(s[0][i] - mn) + __expf(s[1][i] - mn) +
                      __expf(s[2][i] - mn) + __expf(s[3][i] - mn);
#pragma unroll
            for (int o = 1; o < 16; o <<= 1) e += __shfl_xor(e, o, 16);
            lsum[i] = lsum[i] * __expf(m[i] - mn) + e;
            m[i] = mn;
        }
    }

    float linv[4];
#pragma unroll
    for (int i = 0; i < 4; ++i) linv[i] = 1.0f / lsum[i];

    f32x4 x[4];
#pragma unroll
    for (int dt = 0; dt < 4; ++dt)
#pragma unroll
        for (int e = 0; e < 4; ++e) x[dt][e] = 0.f;

    // ---- pass 2: recompute scores, write attn, PV (P aliases K buffer) ----
    for (int tt = 0; tt < 32; ++tt) {
        const int j0 = tt * 64;
        __syncthreads();                       // prev PV reads (P=buf0, V=buf1) done
#pragma unroll
        for (int p = 0; p < 2; ++p) {
            const int jr = sjr + p * 32;
            lds_st8(&KB[0][0][jr][sc8], *(const f16x8*)(Kh + (size_t)(j0 + jr) * DMODEL + h * DHEAD + sc8));
            lds_st8(&KB[0][1][jr][sc8], *(const f16x8*)(Kl + (size_t)(j0 + jr) * DMODEL + h * DHEAD + sc8));
            lds_st8(&KB[1][0][jr][sc8], *(const f16x8*)(Vth + (size_t)(h * DHEAD + jr) * NTOK + j0 + sc8));
            lds_st8(&KB[1][1][jr][sc8], *(const f16x8*)(Vtl + (size_t)(h * DHEAD + jr) * NTOK + j0 + sc8));
        }
        __syncthreads();

        f32x4 s[4];
#pragma unroll
        for (int jt = 0; jt < 4; ++jt)
#pragma unroll
            for (int e = 0; e < 4; ++e) s[jt][e] = 0.f;
        __builtin_amdgcn_s_setprio(1);
#pragma unroll
        for (int jt = 0; jt < 4; ++jt)
#pragma unroll
            for (int ks = 0; ks < 2; ++ks) {
                const f16x8 kh = lds_ld8(&KB[0][0][jt * 16 + lr][ks * 32 + lk * 8]);
                const f16x8 kl = lds_ld8(&KB[0][1][jt * 16 + lr][ks * 32 + lk * 8]);
                s[jt] = __builtin_amdgcn_mfma_f32_16x16x32_f16(qh[ks], kh, s[jt], 0, 0, 0);
                s[jt] = __builtin_amdgcn_mfma_f32_16x16x32_f16(qh[ks], kl, s[jt], 0, 0, 0);
                s[jt] = __builtin_amdgcn_mfma_f32_16x16x32_f16(qlo[ks], kh, s[jt], 0, 0, 0);
            }
        __builtin_amdgcn_s_setprio(0);
        __syncthreads();                       // all K reads done before P overwrites buf0

#pragma unroll
        for (int jt = 0; jt < 4; ++jt)
#pragma unroll
            for (int i = 0; i < 4; ++i) {
                const float p = __expf(s[jt][i] - m[i]) * linv[i];
                attn[((size_t)h * NTOK + rw + lk * 4 + i) * NTOK + j0 + jt * 16 + lr] = p;
                _Float16 ph, pl;
                split16(p, ph, pl);
                KB[0][0][wid * 16 + lk * 4 + i][jt * 16 + lr] = ph;   // wave-private rows
                KB[0][1][wid * 16 + lk * 4 + i][jt * 16 + lr] = pl;
            }
        // wave-local P read-back (no barrier needed; lgkmcnt ordering)
        f16x8 pah[2], pal[2];
#pragma unroll
        for (int ks = 0; ks < 2; ++ks) {
            pah[ks] = lds_ld8(&KB[0][0][wid * 16 + lr][ks * 32 + lk * 8]);
            pal[ks] = lds_ld8(&KB[0][1][wid * 16 + lr][ks * 32 + lk * 8]);
        }
        __builtin_amdgcn_s_setprio(1);
#pragma unroll
        for (int dt = 0; dt < 4; ++dt)
#pragma unroll
            for (int ks = 0; ks < 2; ++ks) {
                const f16x8 vh = lds_ld8(&KB[1][0][dt * 16 + lr][ks * 32 + lk * 8]);
                const f16x8 vl = lds_ld8(&KB[1][1][dt * 16 + lr][ks * 32 + lk * 8]);
                x[dt] = __builtin_amdgcn_mfma_f32_16x16x32_f16(pah[ks], vh, x[dt], 0, 0, 0);
                x[dt] = __builtin_amdgcn_mfma_f32_16x16x32_f16(pah[ks], vl, x[dt], 0, 0, 0);
                x[dt] = __builtin_amdgcn_mfma_f32_16x16x32_f16(pal[ks], vh, x[dt], 0, 0, 0);
            }
        __builtin_amdgcn_s_setprio(0);
    }

    // X epilogue -> hi/lo f16 for out-proj
#pragma unroll
    for (int dt = 0; dt < 4; ++dt)
#pragma unroll
        for (int i = 0; i < 4; ++i) {
            const int row = rw + lk * 4 + i;
            const int col = h * DHEAD + dt * 16 + lr;
            _Float16 hh, lo;
            split16(x[dt][i], hh, lo);
            Xh[(size_t)row * DMODEL + col] = hh;
            Xl[(size_t)row * DMODEL + col] = lo;
        }
}

// ---------- output projection: split-f16 MFMA GEMM, f32 epilogue ----------
__global__ void __launch_bounds__(256) out_mfma_kernel(
        const _Float16* __restrict__ Xh, const _Float16* __restrict__ Xl,
        const _Float16* __restrict__ WH, const _Float16* __restrict__ WL,
        const float* __restrict__ bo, float* __restrict__ out) {
    __shared__ _Float16 Ah[128][40], Al[128][40], Bh[128][40], Bl[128][40];
    const int t = threadIdx.x;
    const int l = t & 63, wid = t >> 6;
    const int lr = l & 15, lk = l >> 4;
    const int m0 = blockIdx.y * 128, n0 = blockIdx.x * 128;
    const int wm = (wid >> 1) * 64, wn = (wid & 1) * 64;

    f32x4 acc[4][4];
#pragma unroll
    for (int mi = 0; mi < 4; ++mi)
#pragma unroll
        for (int ni = 0; ni < 4; ++ni)
#pragma unroll
            for (int e = 0; e < 4; ++e) acc[mi][ni][e] = 0.f;

    for (int k0 = 0; k0 < DMODEL; k0 += 32) {
        __syncthreads();
#pragma unroll
        for (int p = 0; p < 2; ++p) {
            const int idx = t + p * 256;
            const int r = idx >> 2, c8 = (idx & 3) * 8;
            *(f16x8*)&Ah[r][c8] = *(const f16x8*)(Xh + (size_t)(m0 + r) * DMODEL + k0 + c8);
            *(f16x8*)&Al[r][c8] = *(const f16x8*)(Xl + (size_t)(m0 + r) * DMODEL + k0 + c8);
            *(f16x8*)&Bh[r][c8] = *(const f16x8*)(WH + (size_t)(n0 + r) * DMODEL + k0 + c8);
            *(f16x8*)&Bl[r][c8] = *(const f16x8*)(WL + (size_t)(n0 + r) * DMODEL + k0 + c8);
        }
        __syncthreads();

        f16x8 ah[4], al[4], bh[4], bl[4];
#pragma unroll
        for (int i = 0; i < 4; ++i) {
            ah[i] = *(f16x8*)&Ah[wm + i * 16 + lr][lk * 8];
            al[i] = *(f16x8*)&Al[wm + i * 16 + lr][lk * 8];
            bh[i] = *(f16x8*)&Bh[wn + i * 16 + lr][lk * 8];
            bl[i] = *(f16x8*)&Bl[wn + i * 16 + lr][lk * 8];
        }
#pragma unroll
        for (int mi = 0; mi < 4; ++mi)
#pragma unroll
            for (int ni = 0; ni < 4; ++ni) {
                acc[mi][ni] = __builtin_amdgcn_mfma_f32_16x16x32_f16(ah[mi], bh[ni], acc[mi][ni], 0, 0, 0);
                acc[mi][ni] = __builtin_amdgcn_mfma_f32_16x16x32_f16(ah[mi], bl[ni], acc[mi][ni], 0, 0, 0);
                acc[mi][ni] = __builtin_amdgcn_mfma_f32_16x16x32_f16(al[mi], bh[ni], acc[mi][ni], 0, 0, 0);
            }
    }

#pragma unroll
    for (int ni = 0; ni < 4; ++ni) {
        const int col = n0 + wn + ni * 16 + lr;
        const float bv_ = bo[col];
#pragma unroll
        for (int mi = 0; mi < 4; ++mi)
#pragma unroll
            for (int i = 0; i < 4; ++i) {
                const int row = m0 + wm + mi * 16 + lk * 4 + i;
                out[(size_t)row * DMODEL + col] = acc[mi][ni][i] + bv_;
            }
    }
}

extern "C" void kernel_launch(void* const* d_in, const int* in_sizes, int n_in,
                              void* d_out, int out_size, void* d_ws, size_t ws_size,
                              hipStream_t stream) {
    (void)in_sizes; (void)n_in; (void)out_size; (void)ws_size;
    const float* query = (const float*)d_in[0];
    const float* key_  = (const float*)d_in[1];
    const float* value = (const float*)d_in[2];
    const float* Wq = (const float*)d_in[3];
    const float* bq = (const float*)d_in[4];
    const float* Wk = (const float*)d_in[5];
    const float* bk = (const float*)d_in[6];
    const float* Wv = (const float*)d_in[7];
    const float* bv = (const float*)d_in[8];
    const float* Wo = (const float*)d_in[9];
    const float* bo = (const float*)d_in[10];

    float* out  = (float*)d_out;
    float* attn = out + (size_t)NTOK * DMODEL;

    const size_t MM = (size_t)1024 * 1024;
    _Float16* ws16 = (_Float16*)d_ws;          // total 24*MM halves = 48 MB
    _Float16* Wt  = ws16;                      // 8 planes (Wq,Wk,Wv,Wo x hi/lo)
    _Float16* Qh  = ws16 + 8 * MM;
    _Float16* Ql  = Qh  + 2 * MM;
    _Float16* Kh_ = Ql  + 2 * MM;
    _Float16* Kl_ = Kh_ + 2 * MM;
    _Float16* Vth = Kl_ + 2 * MM;
    _Float16* Vtl = Vth + 2 * MM;
    _Float16* Xh  = Vtl + 2 * MM;
    _Float16* Xl  = Xh  + 2 * MM;

    dim3 blk(256);
    prep_w_kernel<<<dim3(32, 32, 4), blk, 0, stream>>>(Wq, Wk, Wv, Wo, Wt);
    qkv_mfma_kernel<<<dim3(8, 16, 3), blk, 0, stream>>>(query, key_, value, Wt, bq, bk, bv,
                                                        Qh, Ql, Kh_, Kl_, Vth, Vtl);
    attn_kernel<<<dim3(32, 16), blk, 0, stream>>>(Qh, Ql, Kh_, Kl_, Vth, Vtl, attn, Xh, Xl);
    out_mfma_kernel<<<dim3(8, 16), blk, 0, stream>>>(Xh, Xl, Wt + 6 * MM, Wt + 7 * MM, bo, out);
}